// Round 1
// baseline (30.845 us; speedup 1.0000x reference)
//
#include <hip/hip_runtime.h>
#include <hip/hip_bf16.h>

// LBP encoder: out[n,k,h,w] = sigmoid(img[n,0,clamp(h+dy),clamp(w+dx)] - img[n,0,h,w])
// Offsets k=0..7: (-1,-1),(-1,0),(-1,1),(0,-1),(0,1),(1,-1),(1,0),(1,1)
// N=16, H=W=512. fp32 in/out. Memory-bound target: ~151 MB total traffic.

#define LBP_N 16
#define LBP_H 512
#define LBP_W 512

__global__ __launch_bounds__(256) void lbp_kernel(const float* __restrict__ img,
                                                  float* __restrict__ out) {
    constexpr int H = LBP_H, W = LBP_W;
    // Each thread produces 4 consecutive pixels (float4 store per channel).
    int tid = blockIdx.x * blockDim.x + threadIdx.x;
    int w4 = tid & (W / 4 - 1);          // 128 groups per row
    int h  = (tid >> 7) & (H - 1);       // 512 rows
    int n  = tid >> 16;                  // image index
    int w0 = w4 * 4;

    const float* src = img + (size_t)n * (H * W);
    int hm = max(h - 1, 0);
    int hp = min(h + 1, H - 1);

    // 3 rows x 6 cols neighborhood (w0-1 .. w0+4), edge-replicated.
    float r0[6], r1[6], r2[6];
#pragma unroll
    for (int j = 0; j < 6; ++j) {
        int w = min(max(w0 + j - 1, 0), W - 1);
        r0[j] = src[hm * W + w];
        r1[j] = src[h  * W + w];
        r2[j] = src[hp * W + w];
    }

    float4 res[8];
#pragma unroll
    for (int i = 0; i < 4; ++i) {
        float c = r1[i + 1];
        float v[8] = { r0[i], r0[i + 1], r0[i + 2],
                       r1[i],            r1[i + 2],
                       r2[i], r2[i + 1], r2[i + 2] };
#pragma unroll
        for (int k = 0; k < 8; ++k) {
            float x = v[k] - c;
            // sigmoid via hw exp2: __expf -> v_mul + v_exp_f32, then v_rcp path
            float s = 1.0f / (1.0f + __expf(-x));
            reinterpret_cast<float*>(&res[k])[i] = s;
        }
    }

    float* dst = out + (size_t)n * (8 * H * W) + (size_t)h * W + w0;
#pragma unroll
    for (int k = 0; k < 8; ++k) {
        *reinterpret_cast<float4*>(dst + (size_t)k * (H * W)) = res[k];
    }
}

extern "C" void kernel_launch(void* const* d_in, const int* in_sizes, int n_in,
                              void* d_out, int out_size, void* d_ws, size_t ws_size,
                              hipStream_t stream) {
    const float* img = (const float*)d_in[0];
    float* out = (float*)d_out;
    // total threads = N * H * (W/4) = 16*512*128 = 1,048,576
    int total = LBP_N * LBP_H * (LBP_W / 4);
    int block = 256;
    int grid = total / block;  // 4096
    lbp_kernel<<<grid, block, 0, stream>>>(img, out);
}